// Round 1
// baseline (204.051 us; speedup 1.0000x reference)
//
#include <hip/hip_runtime.h>
#include <math.h>

#define B_ 1024
#define F_ 39
#define K_ 16
#define P_ 741
#define T_ 9139
#define NC_ 9880          // P_ + T_
#define EPS_ 1e-3f
#define LSTR 20           // padded LDS row stride in floats (80 B, float4-aligned)

// -------------------- kernel 1: gather embeddings + linear term --------------------
__global__ __launch_bounds__(128) void gather_k(const int* __restrict__ feats,
                                                const float* __restrict__ w,
                                                const float* __restrict__ v,
                                                float* __restrict__ xv,
                                                float* __restrict__ lterm) {
    int b = blockIdx.x;
    int tid = threadIdx.x;
    __shared__ int   tok[F_];
    __shared__ float wv[F_];
    if (tid < F_) {
        int t = feats[b * F_ + tid];
        tok[tid] = t;
        wv[tid]  = w[t];
    }
    __syncthreads();
#pragma unroll
    for (int it = 0; it < 5; ++it) {
        int idx = tid + it * 128;
        if (idx < F_ * K_) {
            int f = idx >> 4;
            int k = idx & 15;
            xv[b * (F_ * K_) + idx] = v[(size_t)tok[f] * K_ + k];
        }
    }
    if (tid == 0) {
        float s = 0.f;
        for (int f = 0; f < F_; ++f) s += wv[f];
        lterm[b] = s;
    }
}

// -------------------- kernel 2: column stats (and optional level materialization) ---
template <bool MAT>
__global__ __launch_bounds__(256) void stats_k(const float* __restrict__ xv,
                                               const int* __restrict__ rows,
                                               const int* __restrict__ cols,
                                               const int* __restrict__ i1,
                                               const int* __restrict__ i2,
                                               const int* __restrict__ i3,
                                               float* __restrict__ colsum,
                                               float* __restrict__ colsumsq,
                                               float* __restrict__ levels) {
    __shared__ float lxv[F_ * LSTR];
    int tid = threadIdx.x;
    int col = blockIdx.x * 256 + tid;
    bool valid = col < NC_;
    int oa = 0, ob = 0, oc = -1;
    if (valid) {
        if (col < P_) {
            oa = cols[col] * LSTR;
            ob = rows[col] * LSTR;
            oc = -1;
        } else {
            int t = col - P_;
            oa = i1[t] * LSTR;
            ob = i2[t] * LSTR;
            oc = i3[t] * LSTR;
        }
    }
    float s1 = 0.f, s2 = 0.f;
    int bbase = blockIdx.y * 64;
    for (int bi = 0; bi < 64; ++bi) {
        int b = bbase + bi;
        const float* g = xv + (size_t)b * (F_ * K_);
        for (int idx = tid; idx < F_ * K_; idx += 256)
            lxv[(idx >> 4) * LSTR + (idx & 15)] = g[idx];
        __syncthreads();
        if (valid) {
            float x = 0.f;
            if (oc < 0) {
#pragma unroll
                for (int q = 0; q < 4; ++q) {
                    float4 a = *(const float4*)&lxv[oa + 4 * q];
                    float4 c = *(const float4*)&lxv[ob + 4 * q];
                    x += a.x * c.x + a.y * c.y + a.z * c.z + a.w * c.w;
                }
            } else {
#pragma unroll
                for (int q = 0; q < 4; ++q) {
                    float4 a = *(const float4*)&lxv[oa + 4 * q];
                    float4 c = *(const float4*)&lxv[ob + 4 * q];
                    float4 d = *(const float4*)&lxv[oc + 4 * q];
                    x += a.x * c.x * d.x + a.y * c.y * d.y + a.z * c.z * d.z + a.w * c.w * d.w;
                }
            }
            s1 += x;
            s2 += x * x;
            if (MAT) levels[(size_t)b * NC_ + col] = x;
        }
        __syncthreads();
    }
    if (valid) {
        atomicAdd(&colsum[col], s1);
        atomicAdd(&colsumsq[col], s2);
    }
}

// -------------------- kernel 3: BN finalize -> per-column scale + scalar C ----------
__global__ __launch_bounds__(256) void finalize_k(const float* __restrict__ colsum,
                                                  const float* __restrict__ colsumsq,
                                                  const float* __restrict__ gamma2,
                                                  const float* __restrict__ beta2,
                                                  const float* __restrict__ gw2,
                                                  const float* __restrict__ gamma3,
                                                  const float* __restrict__ beta3,
                                                  const float* __restrict__ gw3,
                                                  float* __restrict__ scale,
                                                  float* __restrict__ Cacc) {
    int col = blockIdx.x * 256 + threadIdx.x;
    float c = 0.f;
    if (col < NC_) {
        float mean = colsum[col] * (1.0f / B_);
        float var  = colsumsq[col] * (1.0f / B_) - mean * mean;
        float inv  = 1.0f / sqrtf(var + EPS_);
        float g, be, gw;
        if (col < P_) {
            g = gamma2[col]; be = beta2[col]; gw = gw2[col];
        } else {
            int t = col - P_;
            g = gamma3[t]; be = beta3[t]; gw = gw3[t];
        }
        scale[col] = gw * g * inv;
        c = gw * (be - g * inv * mean);
    }
    __shared__ float red[256];
    red[threadIdx.x] = c;
    __syncthreads();
    for (int s = 128; s > 0; s >>= 1) {
        if (threadIdx.x < s) red[threadIdx.x] += red[threadIdx.x + s];
        __syncthreads();
    }
    if (threadIdx.x == 0) atomicAdd(Cacc, red[0]);
}

// -------------------- kernel 4: per-batch weighted sum ------------------------------
template <bool MAT>
__global__ __launch_bounds__(256) void final_k(const float* __restrict__ xv,
                                               const float* __restrict__ levels,
                                               const int* __restrict__ rows,
                                               const int* __restrict__ cols,
                                               const int* __restrict__ i1,
                                               const int* __restrict__ i2,
                                               const int* __restrict__ i3,
                                               const float* __restrict__ scale,
                                               const float* __restrict__ lterm,
                                               const float* __restrict__ Cacc,
                                               const float* __restrict__ bias,
                                               float* __restrict__ out) {
    int b = blockIdx.x, tid = threadIdx.x;
    float acc = 0.f;
    __shared__ float lxv[F_ * LSTR];
    if (MAT) {
        const float* lv = levels + (size_t)b * NC_;
        for (int col = tid; col < NC_; col += 256) acc += scale[col] * lv[col];
    } else {
        const float* g = xv + (size_t)b * (F_ * K_);
        for (int idx = tid; idx < F_ * K_; idx += 256)
            lxv[(idx >> 4) * LSTR + (idx & 15)] = g[idx];
        __syncthreads();
        for (int p = tid; p < P_; p += 256) {
            int oa = cols[p] * LSTR, ob = rows[p] * LSTR;
            float x = 0.f;
#pragma unroll
            for (int q = 0; q < 4; ++q) {
                float4 a = *(const float4*)&lxv[oa + 4 * q];
                float4 c = *(const float4*)&lxv[ob + 4 * q];
                x += a.x * c.x + a.y * c.y + a.z * c.z + a.w * c.w;
            }
            acc += scale[p] * x;
        }
        for (int t = tid; t < T_; t += 256) {
            int oa = i1[t] * LSTR, ob = i2[t] * LSTR, oc = i3[t] * LSTR;
            float x = 0.f;
#pragma unroll
            for (int q = 0; q < 4; ++q) {
                float4 a = *(const float4*)&lxv[oa + 4 * q];
                float4 c = *(const float4*)&lxv[ob + 4 * q];
                float4 d = *(const float4*)&lxv[oc + 4 * q];
                x += a.x * c.x * d.x + a.y * c.y * d.y + a.z * c.z * d.z + a.w * c.w * d.w;
            }
            acc += scale[P_ + t] * x;
        }
    }
    __shared__ float red[256];
    red[tid] = acc;
    __syncthreads();
    for (int s = 128; s > 0; s >>= 1) {
        if (tid < s) red[tid] += red[tid + s];
        __syncthreads();
    }
    if (tid == 0) out[b] = red[0] + lterm[b] + Cacc[0] + bias[0];
}

// -------------------- host launcher -------------------------------------------------
extern "C" void kernel_launch(void* const* d_in, const int* in_sizes, int n_in,
                              void* d_out, int out_size, void* d_ws, size_t ws_size,
                              hipStream_t stream) {
    const int*   feats  = (const int*)d_in[0];
    const float* w      = (const float*)d_in[1];
    const float* v      = (const float*)d_in[2];
    const float* bias   = (const float*)d_in[3];
    const float* gamma2 = (const float*)d_in[4];
    const float* beta2  = (const float*)d_in[5];
    const float* gw2    = (const float*)d_in[6];
    const float* gamma3 = (const float*)d_in[7];
    const float* beta3  = (const float*)d_in[8];
    const float* gw3    = (const float*)d_in[9];
    const int*   rows   = (const int*)d_in[10];
    const int*   cols   = (const int*)d_in[11];
    const int*   i1     = (const int*)d_in[12];
    const int*   i2     = (const int*)d_in[13];
    const int*   i3     = (const int*)d_in[14];
    float*       out    = (float*)d_out;
    float*       ws     = (float*)d_ws;

    // workspace layout (float offsets)
    float* xv       = ws;                 // 1024*39*16 = 638976
    float* lterm    = ws + 638976;        // 1024
    float* scale    = ws + 640000;        // 9880
    float* colsum   = ws + 649880;        // 9880
    float* colsumsq = ws + 659760;        // 9880
    float* Cacc     = ws + 669640;        // 1
    float* levels   = ws + 669648;        // optional: 1024*9880 floats
    size_t need_big = ((size_t)669648 + (size_t)B_ * NC_) * sizeof(float);
    bool mat = ws_size >= need_big;       // ws_size is constant per-harness -> same path every call

    // zero colsum, colsumsq, Cacc (contiguous: 2*9880+1 floats)
    hipMemsetAsync(colsum, 0, (size_t)(2 * NC_ + 1) * sizeof(float), stream);

    gather_k<<<B_, 128, 0, stream>>>(feats, w, v, xv, lterm);

    dim3 sgrid((NC_ + 255) / 256, 16);  // 39 col-chunks x 16 batch-chunks of 64
    if (mat)
        stats_k<true><<<sgrid, 256, 0, stream>>>(xv, rows, cols, i1, i2, i3,
                                                 colsum, colsumsq, levels);
    else
        stats_k<false><<<sgrid, 256, 0, stream>>>(xv, rows, cols, i1, i2, i3,
                                                  colsum, colsumsq, levels);

    finalize_k<<<(NC_ + 255) / 256, 256, 0, stream>>>(colsum, colsumsq,
                                                      gamma2, beta2, gw2,
                                                      gamma3, beta3, gw3,
                                                      scale, Cacc);

    if (mat)
        final_k<true><<<B_, 256, 0, stream>>>(xv, levels, rows, cols, i1, i2, i3,
                                              scale, lterm, Cacc, bias, out);
    else
        final_k<false><<<B_, 256, 0, stream>>>(xv, levels, rows, cols, i1, i2, i3,
                                               scale, lterm, Cacc, bias, out);
}

// Round 2
// 183.884 us; speedup vs baseline: 1.1097x; 1.1097x over previous
//
#include <hip/hip_runtime.h>
#include <math.h>

#define B_ 1024
#define F_ 39
#define K_ 16
#define P_ 741
#define T_ 9139
#define NC_ 9880          // P_ + T_
#define EPS_ 1e-3f
#define LSTR 20           // padded LDS embedding row stride in floats
#define LS 9920           // levels row stride (floats); 9920*4 B = 39680 B, 128 B aligned
#define SPLIT 4940        // columns per block-split (2 splits cover 9880)
#define CHUNK 20          // contiguous columns per thread (256*20 >= 4940)

// -------------------- kernel 1: gather embeddings + linear term --------------------
__global__ __launch_bounds__(128) void gather_k(const int* __restrict__ feats,
                                                const float* __restrict__ w,
                                                const float* __restrict__ v,
                                                float* __restrict__ xv,
                                                float* __restrict__ lterm) {
    int b = blockIdx.x;
    int tid = threadIdx.x;
    __shared__ int   tok[F_];
    __shared__ float wv[F_];
    if (tid < F_) {
        int t = feats[b * F_ + tid];
        tok[tid] = t;
        wv[tid]  = w[t];
    }
    __syncthreads();
#pragma unroll
    for (int it = 0; it < 5; ++it) {
        int idx = tid + it * 128;
        if (idx < F_ * K_) {
            int f = idx >> 4;
            int k = idx & 15;
            xv[b * (F_ * K_) + idx] = v[(size_t)tok[f] * K_ + k];
        }
    }
    if (tid == 0) {
        float s = 0.f;
        for (int f = 0; f < F_; ++f) s += wv[f];
        lterm[b] = s;
    }
}

// -------------------- kernel 1b: pack column indices into one u32 ------------------
// pk = off1 | off2<<10 | off3<<20, offX = field_index * LSTR (max 760, fits 10 bits)
__global__ __launch_bounds__(256) void pack_k(const int* __restrict__ rows,
                                              const int* __restrict__ cols,
                                              const int* __restrict__ i1,
                                              const int* __restrict__ i2,
                                              const int* __restrict__ i3,
                                              unsigned* __restrict__ pidx) {
    int c = blockIdx.x * 256 + threadIdx.x;
    if (c >= NC_) return;
    unsigned pk;
    if (c < P_) {
        pk = (unsigned)(cols[c] * LSTR) | ((unsigned)(rows[c] * LSTR) << 10);
    } else {
        int t = c - P_;
        pk = (unsigned)(i1[t] * LSTR) | ((unsigned)(i2[t] * LSTR) << 10)
           | ((unsigned)(i3[t] * LSTR) << 20);
    }
    pidx[c] = pk;
}

// -------------------- kernel 2: compute level values, one batch row per block ------
__global__ __launch_bounds__(256) void levels_k(const float* __restrict__ xv,
                                                const unsigned* __restrict__ pidx,
                                                float* __restrict__ levels) {
    int b = blockIdx.x;
    int cbase = blockIdx.y * SPLIT;
    int cend = cbase + SPLIT;           // 2*4940 = 9880 exactly
    int tid = threadIdx.x;
    __shared__ float emb[F_ * LSTR];    // 780 floats
    __shared__ float buf[SPLIT];        // 4940 floats

    const float* g = xv + (size_t)b * (F_ * K_);
    for (int idx = tid; idx < F_ * K_; idx += 256)
        emb[(idx >> 4) * LSTR + (idx & 15)] = g[idx];
    __syncthreads();

    int start = cbase + tid * CHUNK;
    int end = start + CHUNK;
    if (end > cend) end = cend;

    unsigned cur = 0xFFFFFFFFu;
    float4 Y0, Y1, Y2, Y3;
    for (int col = start; col < end; ++col) {
        unsigned pk = pidx[col];
        int o1 = (int)(pk & 1023u);
        int o2 = (int)((pk >> 10) & 1023u);
        float x;
        if (col < P_) {
            float4 a0 = *(const float4*)&emb[o1 + 0];
            float4 a1 = *(const float4*)&emb[o1 + 4];
            float4 a2 = *(const float4*)&emb[o1 + 8];
            float4 a3 = *(const float4*)&emb[o1 + 12];
            float4 c0 = *(const float4*)&emb[o2 + 0];
            float4 c1 = *(const float4*)&emb[o2 + 4];
            float4 c2 = *(const float4*)&emb[o2 + 8];
            float4 c3 = *(const float4*)&emb[o2 + 12];
            x = a0.x*c0.x + a0.y*c0.y + a0.z*c0.z + a0.w*c0.w
              + a1.x*c1.x + a1.y*c1.y + a1.z*c1.z + a1.w*c1.w
              + a2.x*c2.x + a2.y*c2.y + a2.z*c2.z + a2.w*c2.w
              + a3.x*c3.x + a3.y*c3.y + a3.z*c3.z + a3.w*c3.w;
        } else {
            unsigned key = pk & 0xFFFFFu;
            if (key != cur) {
                cur = key;
                float4 a0 = *(const float4*)&emb[o1 + 0];
                float4 a1 = *(const float4*)&emb[o1 + 4];
                float4 a2 = *(const float4*)&emb[o1 + 8];
                float4 a3 = *(const float4*)&emb[o1 + 12];
                float4 c0 = *(const float4*)&emb[o2 + 0];
                float4 c1 = *(const float4*)&emb[o2 + 4];
                float4 c2 = *(const float4*)&emb[o2 + 8];
                float4 c3 = *(const float4*)&emb[o2 + 12];
                Y0 = make_float4(a0.x*c0.x, a0.y*c0.y, a0.z*c0.z, a0.w*c0.w);
                Y1 = make_float4(a1.x*c1.x, a1.y*c1.y, a1.z*c1.z, a1.w*c1.w);
                Y2 = make_float4(a2.x*c2.x, a2.y*c2.y, a2.z*c2.z, a2.w*c2.w);
                Y3 = make_float4(a3.x*c3.x, a3.y*c3.y, a3.z*c3.z, a3.w*c3.w);
            }
            int o3 = (int)(pk >> 20);
            float4 d0 = *(const float4*)&emb[o3 + 0];
            float4 d1 = *(const float4*)&emb[o3 + 4];
            float4 d2 = *(const float4*)&emb[o3 + 8];
            float4 d3 = *(const float4*)&emb[o3 + 12];
            x = Y0.x*d0.x + Y0.y*d0.y + Y0.z*d0.z + Y0.w*d0.w
              + Y1.x*d1.x + Y1.y*d1.y + Y1.z*d1.z + Y1.w*d1.w
              + Y2.x*d2.x + Y2.y*d2.y + Y2.z*d2.z + Y2.w*d2.w
              + Y3.x*d3.x + Y3.y*d3.y + Y3.z*d3.z + Y3.w*d3.w;
        }
        buf[col - cbase] = x;
    }
    __syncthreads();

    // coalesced float4 flush: SPLIT = 4940 = 1235 float4s
    float* dst = levels + (size_t)b * LS + cbase;
    for (int idx = tid * 4; idx < SPLIT; idx += 1024)
        *(float4*)&dst[idx] = *(const float4*)&buf[idx];
}

// -------------------- kernel 3: column stats over levels ---------------------------
__global__ __launch_bounds__(256) void stats2_k(const float* __restrict__ levels,
                                                float* __restrict__ colsum,
                                                float* __restrict__ colsumsq) {
    int col = blockIdx.x * 256 + threadIdx.x;
    if (col >= NC_) return;
    const float* p = levels + (size_t)(blockIdx.y * 64) * LS + col;
    float s1 = 0.f, s2 = 0.f;
#pragma unroll 4
    for (int bi = 0; bi < 64; ++bi) {
        float x = p[(size_t)bi * LS];
        s1 += x;
        s2 += x * x;
    }
    atomicAdd(&colsum[col], s1);
    atomicAdd(&colsumsq[col], s2);
}

// -------------------- kernel 4: BN finalize -> per-column scale + scalar C ---------
__global__ __launch_bounds__(256) void finalize_k(const float* __restrict__ colsum,
                                                  const float* __restrict__ colsumsq,
                                                  const float* __restrict__ gamma2,
                                                  const float* __restrict__ beta2,
                                                  const float* __restrict__ gw2,
                                                  const float* __restrict__ gamma3,
                                                  const float* __restrict__ beta3,
                                                  const float* __restrict__ gw3,
                                                  float* __restrict__ scale,
                                                  float* __restrict__ Cacc) {
    int col = blockIdx.x * 256 + threadIdx.x;
    float c = 0.f;
    if (col < NC_) {
        float mean = colsum[col] * (1.0f / B_);
        float var  = colsumsq[col] * (1.0f / B_) - mean * mean;
        float inv  = 1.0f / sqrtf(var + EPS_);
        float g, be, gw;
        if (col < P_) {
            g = gamma2[col]; be = beta2[col]; gw = gw2[col];
        } else {
            int t = col - P_;
            g = gamma3[t]; be = beta3[t]; gw = gw3[t];
        }
        scale[col] = gw * g * inv;
        c = gw * (be - g * inv * mean);
    }
    __shared__ float red[256];
    red[threadIdx.x] = c;
    __syncthreads();
    for (int s = 128; s > 0; s >>= 1) {
        if (threadIdx.x < s) red[threadIdx.x] += red[threadIdx.x + s];
        __syncthreads();
    }
    if (threadIdx.x == 0) atomicAdd(Cacc, red[0]);
}

// -------------------- kernel 5: weighted row sum -> logits -------------------------
__global__ __launch_bounds__(256) void out_k(const float* __restrict__ levels,
                                             const float* __restrict__ scale,
                                             const float* __restrict__ lterm,
                                             const float* __restrict__ Cacc,
                                             const float* __restrict__ bias,
                                             float* __restrict__ out) {
    int b = blockIdx.x, tid = threadIdx.x;
    const float* p = levels + (size_t)b * LS;
    float acc = 0.f;
    for (int col = tid; col < NC_; col += 256)
        acc += scale[col] * p[col];
    __shared__ float red[256];
    red[tid] = acc;
    __syncthreads();
    for (int s = 128; s > 0; s >>= 1) {
        if (tid < s) red[tid] += red[tid + s];
        __syncthreads();
    }
    if (tid == 0) out[b] = red[0] + lterm[b] + Cacc[0] + bias[0];
}

// -------------------- fallback kernels (small workspace): round-1 path -------------
__global__ __launch_bounds__(256) void stats_fb(const float* __restrict__ xv,
                                                const int* __restrict__ rows,
                                                const int* __restrict__ cols,
                                                const int* __restrict__ i1,
                                                const int* __restrict__ i2,
                                                const int* __restrict__ i3,
                                                float* __restrict__ colsum,
                                                float* __restrict__ colsumsq) {
    __shared__ float lxv[F_ * LSTR];
    int tid = threadIdx.x;
    int col = blockIdx.x * 256 + tid;
    bool valid = col < NC_;
    int oa = 0, ob = 0, oc = -1;
    if (valid) {
        if (col < P_) { oa = cols[col] * LSTR; ob = rows[col] * LSTR; oc = -1; }
        else { int t = col - P_; oa = i1[t] * LSTR; ob = i2[t] * LSTR; oc = i3[t] * LSTR; }
    }
    float s1 = 0.f, s2 = 0.f;
    int bbase = blockIdx.y * 64;
    for (int bi = 0; bi < 64; ++bi) {
        int b = bbase + bi;
        const float* g = xv + (size_t)b * (F_ * K_);
        for (int idx = tid; idx < F_ * K_; idx += 256)
            lxv[(idx >> 4) * LSTR + (idx & 15)] = g[idx];
        __syncthreads();
        if (valid) {
            float x = 0.f;
            if (oc < 0) {
#pragma unroll
                for (int q = 0; q < 4; ++q) {
                    float4 a = *(const float4*)&lxv[oa + 4 * q];
                    float4 c = *(const float4*)&lxv[ob + 4 * q];
                    x += a.x * c.x + a.y * c.y + a.z * c.z + a.w * c.w;
                }
            } else {
#pragma unroll
                for (int q = 0; q < 4; ++q) {
                    float4 a = *(const float4*)&lxv[oa + 4 * q];
                    float4 c = *(const float4*)&lxv[ob + 4 * q];
                    float4 d = *(const float4*)&lxv[oc + 4 * q];
                    x += a.x * c.x * d.x + a.y * c.y * d.y + a.z * c.z * d.z + a.w * c.w * d.w;
                }
            }
            s1 += x; s2 += x * x;
        }
        __syncthreads();
    }
    if (valid) { atomicAdd(&colsum[col], s1); atomicAdd(&colsumsq[col], s2); }
}

__global__ __launch_bounds__(256) void final_fb(const float* __restrict__ xv,
                                                const int* __restrict__ rows,
                                                const int* __restrict__ cols,
                                                const int* __restrict__ i1,
                                                const int* __restrict__ i2,
                                                const int* __restrict__ i3,
                                                const float* __restrict__ scale,
                                                const float* __restrict__ lterm,
                                                const float* __restrict__ Cacc,
                                                const float* __restrict__ bias,
                                                float* __restrict__ out) {
    int b = blockIdx.x, tid = threadIdx.x;
    float acc = 0.f;
    __shared__ float lxv[F_ * LSTR];
    const float* g = xv + (size_t)b * (F_ * K_);
    for (int idx = tid; idx < F_ * K_; idx += 256)
        lxv[(idx >> 4) * LSTR + (idx & 15)] = g[idx];
    __syncthreads();
    for (int p = tid; p < P_; p += 256) {
        int oa = cols[p] * LSTR, ob = rows[p] * LSTR;
        float x = 0.f;
#pragma unroll
        for (int q = 0; q < 4; ++q) {
            float4 a = *(const float4*)&lxv[oa + 4 * q];
            float4 c = *(const float4*)&lxv[ob + 4 * q];
            x += a.x * c.x + a.y * c.y + a.z * c.z + a.w * c.w;
        }
        acc += scale[p] * x;
    }
    for (int t = tid; t < T_; t += 256) {
        int oa = i1[t] * LSTR, ob = i2[t] * LSTR, oc = i3[t] * LSTR;
        float x = 0.f;
#pragma unroll
        for (int q = 0; q < 4; ++q) {
            float4 a = *(const float4*)&lxv[oa + 4 * q];
            float4 c = *(const float4*)&lxv[ob + 4 * q];
            float4 d = *(const float4*)&lxv[oc + 4 * q];
            x += a.x * c.x * d.x + a.y * c.y * d.y + a.z * c.z * d.z + a.w * c.w * d.w;
        }
        acc += scale[P_ + t] * x;
    }
    __shared__ float red[256];
    red[tid] = acc;
    __syncthreads();
    for (int s = 128; s > 0; s >>= 1) {
        if (tid < s) red[tid] += red[tid + s];
        __syncthreads();
    }
    if (tid == 0) out[b] = red[0] + lterm[b] + Cacc[0] + bias[0];
}

// -------------------- host launcher ------------------------------------------------
extern "C" void kernel_launch(void* const* d_in, const int* in_sizes, int n_in,
                              void* d_out, int out_size, void* d_ws, size_t ws_size,
                              hipStream_t stream) {
    const int*   feats  = (const int*)d_in[0];
    const float* w      = (const float*)d_in[1];
    const float* v      = (const float*)d_in[2];
    const float* bias   = (const float*)d_in[3];
    const float* gamma2 = (const float*)d_in[4];
    const float* beta2  = (const float*)d_in[5];
    const float* gw2    = (const float*)d_in[6];
    const float* gamma3 = (const float*)d_in[7];
    const float* beta3  = (const float*)d_in[8];
    const float* gw3    = (const float*)d_in[9];
    const int*   rows   = (const int*)d_in[10];
    const int*   cols   = (const int*)d_in[11];
    const int*   i1     = (const int*)d_in[12];
    const int*   i2     = (const int*)d_in[13];
    const int*   i3     = (const int*)d_in[14];
    float*       out    = (float*)d_out;
    float*       ws     = (float*)d_ws;

    // workspace layout (float offsets)
    float*    xv       = ws;              // 638976
    float*    lterm    = ws + 638976;     // 1024
    float*    scale    = ws + 640000;     // 9880
    float*    colsum   = ws + 649880;     // 9880
    float*    colsumsq = ws + 659760;     // 9880
    float*    Cacc     = ws + 669640;     // 1
    unsigned* pidx     = (unsigned*)(ws + 669696); // 9880 ints, 128B-aligned
    float*    levels   = ws + 679680;     // 1024 * 9920, 128B-aligned
    size_t need_big = ((size_t)679680 + (size_t)B_ * LS) * sizeof(float);
    bool mat = ws_size >= need_big;       // ws_size constant -> same path every call

    hipMemsetAsync(colsum, 0, (size_t)(2 * NC_ + 1) * sizeof(float), stream);

    gather_k<<<B_, 128, 0, stream>>>(feats, w, v, xv, lterm);

    if (mat) {
        pack_k<<<(NC_ + 255) / 256, 256, 0, stream>>>(rows, cols, i1, i2, i3, pidx);
        levels_k<<<dim3(B_, 2), 256, 0, stream>>>(xv, pidx, levels);
        stats2_k<<<dim3((NC_ + 255) / 256, 16), 256, 0, stream>>>(levels, colsum, colsumsq);
        finalize_k<<<(NC_ + 255) / 256, 256, 0, stream>>>(colsum, colsumsq,
                                                          gamma2, beta2, gw2,
                                                          gamma3, beta3, gw3, scale, Cacc);
        out_k<<<B_, 256, 0, stream>>>(levels, scale, lterm, Cacc, bias, out);
    } else {
        stats_fb<<<dim3((NC_ + 255) / 256, 16), 256, 0, stream>>>(xv, rows, cols, i1, i2, i3,
                                                                  colsum, colsumsq);
        finalize_k<<<(NC_ + 255) / 256, 256, 0, stream>>>(colsum, colsumsq,
                                                          gamma2, beta2, gw2,
                                                          gamma3, beta3, gw3, scale, Cacc);
        final_fb<<<B_, 256, 0, stream>>>(xv, rows, cols, i1, i2, i3,
                                         scale, lterm, Cacc, bias, out);
    }
}

// Round 3
// 152.461 us; speedup vs baseline: 1.3384x; 1.2061x over previous
//
#include <hip/hip_runtime.h>
#include <math.h>

#define B_ 1024
#define F_ 39
#define K_ 16
#define P_ 741
#define T_ 9139
#define NC_ 9880          // P_ + T_
#define EPS_ 1e-3f
#define ESTR 18           // emb row stride (floats): (9f+j) mod 16 spreads b64 slots
#define LS2 9920          // levels row stride in bf16 elems (19840 B, 64 B aligned)

__device__ __forceinline__ unsigned short to_bf16(float x) {
    unsigned u = __float_as_uint(x);
    u += 0x7fffu + ((u >> 16) & 1u);   // round-to-nearest-even
    return (unsigned short)(u >> 16);
}
__device__ __forceinline__ float from_bf16(unsigned short h) {
    return __uint_as_float(((unsigned)h) << 16);
}

// ---------- kernel 0: pack column indices -------------------------------------------
// pairs  (c < P_):  pk = (cols[c]*ESTR) | (rows[c]*ESTR)<<10     (both <= 684)
// triples(c >= P_): pk = pair_idx(i1,i2) | (i3*ESTR)<<10          (pair_idx <= 740)
__global__ __launch_bounds__(256) void pack_k(const int* __restrict__ rows,
                                              const int* __restrict__ cols,
                                              const int* __restrict__ i1,
                                              const int* __restrict__ i2,
                                              const int* __restrict__ i3,
                                              unsigned* __restrict__ pidx) {
    int c = blockIdx.x * 256 + threadIdx.x;
    if (c >= NC_) return;
    unsigned pk;
    if (c < P_) {
        pk = (unsigned)(cols[c] * ESTR) | ((unsigned)(rows[c] * ESTR) << 10);
    } else {
        int t = c - P_;
        int a = i1[t], b = i2[t], cc = i3[t];
        int p = a * (2 * F_ - 1 - a) / 2 + (b - a - 1);   // lex pair index of (a,b)
        pk = (unsigned)p | ((unsigned)(cc * ESTR) << 10);
    }
    pidx[c] = pk;
}

// ---------- kernel 1: fused gather + pair products + all level values (bf16) --------
// One batch row per block. emb (stride-18) + Y (741x16) + bf16 staging buf in LDS.
__global__ __launch_bounds__(256) void levels_k(const int* __restrict__ feats,
                                                const float* __restrict__ v,
                                                const unsigned* __restrict__ pidx,
                                                unsigned short* __restrict__ levels) {
    int b = blockIdx.x;
    int tid = threadIdx.x;
    __shared__ int   tok[F_];
    __shared__ float emb[F_ * ESTR];          // 2808 B
    __shared__ float Y[P_ * K_];              // 47424 B
    __shared__ unsigned short buf[LS2];       // 19840 B

    if (tid < F_) tok[tid] = feats[b * F_ + tid];
    __syncthreads();
    for (int idx = tid; idx < F_ * K_; idx += 256) {
        int f = idx >> 4, k = idx & 15;
        emb[f * ESTR + k] = v[(size_t)tok[f] * K_ + k];
    }
    __syncthreads();

    // P0: all 741 pair products -> Y, and level2 = sum_k Y
    for (int p = tid; p < P_; p += 256) {
        unsigned pk = pidx[p];
        int o1 = (int)(pk & 1023u);
        int o2 = (int)((pk >> 10) & 1023u);
        float s = 0.f;
#pragma unroll
        for (int j = 0; j < 8; ++j) {
            float2 a = *(const float2*)&emb[o1 + 2 * j];
            float2 c = *(const float2*)&emb[o2 + 2 * j];
            float2 y = make_float2(a.x * c.x, a.y * c.y);
            *(float2*)&Y[p * K_ + 2 * j] = y;
            s += y.x + y.y;
        }
        buf[p] = to_bf16(s);
    }
    __syncthreads();

    // P1: triples, branch-free: x = <Y[p], emb[i3]>
#pragma unroll 1
    for (int i = 0; i < (T_ + 255) / 256; ++i) {
        int t = i * 256 + tid;
        if (t < T_) {
            unsigned pk = pidx[P_ + t];
            int p  = (int)(pk & 1023u);
            int o3 = (int)((pk >> 10) & 1023u);
            float s = 0.f;
#pragma unroll
            for (int j = 0; j < 8; ++j) {
                float2 y = *(const float2*)&Y[p * K_ + 2 * j];
                float2 e = *(const float2*)&emb[o3 + 2 * j];
                s += y.x * e.x + y.y * e.y;
            }
            buf[P_ + t] = to_bf16(s);
        }
    }
    if (tid < LS2 - NC_) buf[NC_ + tid] = 0;   // pad tail
    __syncthreads();

    // coalesced flush: LS2 ushorts = 1240 uint4
    uint4* dst = (uint4*)(levels + (size_t)b * LS2);
    const uint4* src = (const uint4*)buf;
    for (int idx = tid; idx < LS2 / 8; idx += 256)
        dst[idx] = src[idx];
}

// ---------- kernel 2: column stats over bf16 levels ---------------------------------
__global__ __launch_bounds__(256) void stats2_k(const unsigned short* __restrict__ levels,
                                                float* __restrict__ colsum,
                                                float* __restrict__ colsumsq) {
    int col = blockIdx.x * 256 + threadIdx.x;
    if (col >= NC_) return;
    const unsigned short* p = levels + (size_t)(blockIdx.y * 16) * LS2 + col;
    float s1 = 0.f, s2 = 0.f;
#pragma unroll
    for (int r = 0; r < 16; ++r) {
        float x = from_bf16(p[(size_t)r * LS2]);
        s1 += x;
        s2 += x * x;
    }
    atomicAdd(&colsum[col], s1);
    atomicAdd(&colsumsq[col], s2);
}

// ---------- kernel 3: BN finalize -> per-column scale + scalar C --------------------
__global__ __launch_bounds__(256) void finalize_k(const float* __restrict__ colsum,
                                                  const float* __restrict__ colsumsq,
                                                  const float* __restrict__ gamma2,
                                                  const float* __restrict__ beta2,
                                                  const float* __restrict__ gw2,
                                                  const float* __restrict__ gamma3,
                                                  const float* __restrict__ beta3,
                                                  const float* __restrict__ gw3,
                                                  float* __restrict__ scale,
                                                  float* __restrict__ Cacc) {
    int col = blockIdx.x * 256 + threadIdx.x;
    float c = 0.f;
    if (col < NC_) {
        float mean = colsum[col] * (1.0f / B_);
        float var  = colsumsq[col] * (1.0f / B_) - mean * mean;
        float inv  = 1.0f / sqrtf(var + EPS_);
        float g, be, gw;
        if (col < P_) {
            g = gamma2[col]; be = beta2[col]; gw = gw2[col];
        } else {
            int t = col - P_;
            g = gamma3[t]; be = beta3[t]; gw = gw3[t];
        }
        scale[col] = gw * g * inv;
        c = gw * (be - g * inv * mean);
    }
    __shared__ float red[256];
    red[threadIdx.x] = c;
    __syncthreads();
    for (int s = 128; s > 0; s >>= 1) {
        if (threadIdx.x < s) red[threadIdx.x] += red[threadIdx.x + s];
        __syncthreads();
    }
    if (threadIdx.x == 0) atomicAdd(Cacc, red[0]);
}

// ---------- kernel 4: weighted row sum + linear term -> logits ----------------------
__global__ __launch_bounds__(256) void out_k(const unsigned short* __restrict__ levels,
                                             const float* __restrict__ scale,
                                             const int* __restrict__ feats,
                                             const float* __restrict__ w,
                                             const float* __restrict__ Cacc,
                                             const float* __restrict__ bias,
                                             float* __restrict__ out) {
    int b = blockIdx.x, tid = threadIdx.x;
    const uint2* lv = (const uint2*)(levels + (size_t)b * LS2);   // 4 bf16 per uint2
    float acc = 0.f;
    // 9880 bf16 = 2470 uint2 exactly
    for (int idx = tid; idx < 2470; idx += 256) {
        uint2 u = lv[idx];
        int cbase = idx * 4;
        float4 sc = *(const float4*)&scale[cbase];
        float x0 = __uint_as_float(u.x << 16);
        float x1 = __uint_as_float(u.x & 0xffff0000u);
        float x2 = __uint_as_float(u.y << 16);
        float x3 = __uint_as_float(u.y & 0xffff0000u);
        acc += sc.x * x0 + sc.y * x1 + sc.z * x2 + sc.w * x3;
    }
    if (tid < F_) acc += w[feats[b * F_ + tid]];   // linear term
    __shared__ float red[256];
    red[tid] = acc;
    __syncthreads();
    for (int s = 128; s > 0; s >>= 1) {
        if (tid < s) red[tid] += red[tid + s];
        __syncthreads();
    }
    if (tid == 0) out[b] = red[0] + Cacc[0] + bias[0];
}

// ---------- host launcher -----------------------------------------------------------
extern "C" void kernel_launch(void* const* d_in, const int* in_sizes, int n_in,
                              void* d_out, int out_size, void* d_ws, size_t ws_size,
                              hipStream_t stream) {
    const int*   feats  = (const int*)d_in[0];
    const float* w      = (const float*)d_in[1];
    const float* v      = (const float*)d_in[2];
    const float* bias   = (const float*)d_in[3];
    const float* gamma2 = (const float*)d_in[4];
    const float* beta2  = (const float*)d_in[5];
    const float* gw2    = (const float*)d_in[6];
    const float* gamma3 = (const float*)d_in[7];
    const float* beta3  = (const float*)d_in[8];
    const float* gw3    = (const float*)d_in[9];
    const int*   rows   = (const int*)d_in[10];
    const int*   cols   = (const int*)d_in[11];
    const int*   i1     = (const int*)d_in[12];
    const int*   i2     = (const int*)d_in[13];
    const int*   i3     = (const int*)d_in[14];
    float*       out    = (float*)d_out;
    float*       ws     = (float*)d_ws;

    // workspace layout (float offsets)
    float*          scale    = ws;                    // 9880
    float*          colsum   = ws + 9880;             // 9880
    float*          colsumsq = ws + 19760;            // 9880
    float*          Cacc     = ws + 29640;            // 1
    unsigned*       pidx     = (unsigned*)(ws + 29696);       // 9880
    unsigned short* levels   = (unsigned short*)(ws + 39680); // 1024*9920 bf16 (~20.3 MB)

    // zero colsum, colsumsq, Cacc (contiguous 19761 floats)
    hipMemsetAsync(colsum, 0, (size_t)(2 * NC_ + 1) * sizeof(float), stream);

    pack_k<<<(NC_ + 255) / 256, 256, 0, stream>>>(rows, cols, i1, i2, i3, pidx);
    levels_k<<<B_, 256, 0, stream>>>(feats, v, pidx, levels);
    stats2_k<<<dim3((NC_ + 255) / 256, B_ / 16), 256, 0, stream>>>(levels, colsum, colsumsq);
    finalize_k<<<(NC_ + 255) / 256, 256, 0, stream>>>(colsum, colsumsq,
                                                      gamma2, beta2, gw2,
                                                      gamma3, beta3, gw3, scale, Cacc);
    out_k<<<B_, 256, 0, stream>>>(levels, scale, feats, w, Cacc, bias, out);
}